// Round 1
// baseline (537.799 us; speedup 1.0000x reference)
//
#include <hip/hip_runtime.h>
#include <stdint.h>

typedef unsigned short u16;
typedef __bf16 bf16x8 __attribute__((ext_vector_type(8)));
typedef float  f32x4  __attribute__((ext_vector_type(4)));
typedef int    i32x4  __attribute__((ext_vector_type(4)));

__device__ __forceinline__ u16 f2bf(float f){
  union{float f; uint32_t u;} v; v.f = f;
  uint32_t r = v.u + 0x7FFFu + ((v.u >> 16) & 1u);
  return (u16)(r >> 16);
}

#define GLDS16(gp, lp) __builtin_amdgcn_global_load_lds( \
    (const __attribute__((address_space(1))) void*)(gp),  \
    (__attribute__((address_space(3))) void*)(lp), 16, 0, 0)

// ---------------- fp32 -> bf16 convert (vectorized, grid-stride) ------------
__global__ __launch_bounds__(256) void cvt_kernel(const float* __restrict__ in,
                                                  u16* __restrict__ out, int n4) {
  int stride = gridDim.x * blockDim.x;
  for (int i = blockIdx.x * blockDim.x + threadIdx.x; i < n4; i += stride) {
    float4 v = ((const float4*)in)[i];
    u16 o0 = f2bf(v.x), o1 = f2bf(v.y), o2 = f2bf(v.z), o3 = f2bf(v.w);
    u16* p = out + (size_t)i * 4;
    uint32_t lo = (uint32_t)o0 | ((uint32_t)o1 << 16);
    uint32_t hi = (uint32_t)o2 | ((uint32_t)o3 << 16);
    ((uint2*)p)[0] = make_uint2(lo, hi);
  }
}

// ---------------- bf16 GEMM, C = A * B^T (+bias)(+resid) --------------------
// A: [M][K] bf16, B: [N][K] bf16.  MODE 0: write bf16 C. MODE 1: write f32 C
// with +resid (residual add) fused.
template <int MODE>
__global__ __launch_bounds__(256) void gemm_bt(
    const u16* __restrict__ A, const u16* __restrict__ B,
    const float* __restrict__ bias,
    u16* __restrict__ Cbf, float* __restrict__ Cf, const float* __restrict__ resid,
    int M, int N, int K) {
  __shared__ u16 Alds[128 * 32];
  __shared__ u16 Blds[128 * 32];
  const int t = threadIdx.x;
  const int w = t >> 6, l = t & 63;
  const int wr = w >> 1, wc = w & 1;
  const int g = l >> 4, r16 = l & 15;
  const int brow = blockIdx.y * 128, bcol = blockIdx.x * 128;

  f32x4 acc[4][4];
#pragma unroll
  for (int mi = 0; mi < 4; mi++)
#pragma unroll
    for (int nj = 0; nj < 4; nj++) acc[mi][nj] = (f32x4){0.f, 0.f, 0.f, 0.f};

  const int c0 = 2 * w, c1 = 2 * w + 1;
  const int srow0 = c0 * 16 + (l >> 2);
  const int srow1 = c1 * 16 + (l >> 2);
  const int scol = (l & 3) * 8;

  for (int kt = 0; kt < K; kt += 32) {
    __syncthreads();
    GLDS16(A + (size_t)(brow + srow0) * K + kt + scol, (char*)Alds + c0 * 1024);
    GLDS16(A + (size_t)(brow + srow1) * K + kt + scol, (char*)Alds + c1 * 1024);
    GLDS16(B + (size_t)(bcol + srow0) * K + kt + scol, (char*)Blds + c0 * 1024);
    GLDS16(B + (size_t)(bcol + srow1) * K + kt + scol, (char*)Blds + c1 * 1024);
    __syncthreads();

    bf16x8 af[4], bfr[4];
#pragma unroll
    for (int mi = 0; mi < 4; mi++)
      af[mi] = *(const bf16x8*)&Alds[(wr * 64 + mi * 16 + r16) * 32 + g * 8];
#pragma unroll
    for (int nj = 0; nj < 4; nj++)
      bfr[nj] = *(const bf16x8*)&Blds[(wc * 64 + nj * 16 + r16) * 32 + g * 8];
#pragma unroll
    for (int mi = 0; mi < 4; mi++)
#pragma unroll
      for (int nj = 0; nj < 4; nj++)
        acc[mi][nj] = __builtin_amdgcn_mfma_f32_16x16x32_bf16(af[mi], bfr[nj], acc[mi][nj], 0, 0, 0);
  }

#pragma unroll
  for (int mi = 0; mi < 4; mi++) {
#pragma unroll
    for (int nj = 0; nj < 4; nj++) {
      int col = bcol + wc * 64 + nj * 16 + r16;
      float bv = bias[col];
#pragma unroll
      for (int rr = 0; rr < 4; rr++) {
        int row = brow + wr * 64 + mi * 16 + g * 4 + rr;
        float v = acc[mi][nj][rr] + bv;
        if (MODE == 0) {
          Cbf[(size_t)row * N + col] = f2bf(v);
        } else {
          v += resid[(size_t)row * N + col];
          Cf[(size_t)row * N + col] = v;
        }
      }
    }
  }
}

// ---------------- causal flash attention -------------------------------------
// qkv: [B*S][3072] bf16 (cols 0:1024 q, 1024:2048 k, 2048:3072 v)
// ctxb: [B*S][1024] bf16 output
__global__ __launch_bounds__(256) void attn_kernel(const u16* __restrict__ qkv,
                                                   u16* __restrict__ ctxb) {
  const int S = 2048, HD3 = 3072;
  const int qb = blockIdx.x, h = blockIdx.y, b = blockIdx.z;
  const int t = threadIdx.x, w = t >> 6, l = t & 63;
  const int g = l >> 4, r16 = l & 15;

  __shared__ u16 Klds[64][72];
  __shared__ u16 Vt[64][72];
  __shared__ u16 Pbuf[4][16][72];

  const int q0 = qb * 64 + w * 16;
  const size_t qoff = (size_t)(b * S + q0 + r16) * HD3 + h * 64 + g * 8;
  bf16x8 qf0 = *(const bf16x8*)(qkv + qoff);
  bf16x8 qf1 = *(const bf16x8*)(qkv + qoff + 32);

  f32x4 ctxa[4];
#pragma unroll
  for (int f = 0; f < 4; f++) ctxa[f] = (f32x4){0.f, 0.f, 0.f, 0.f};
  float mrun[4] = {-1e30f, -1e30f, -1e30f, -1e30f};
  float lrun[4] = {0.f, 0.f, 0.f, 0.f};

  for (int kt = 0; kt <= qb; ++kt) {
    const int k0 = kt * 64;
    __syncthreads();
#pragma unroll
    for (int i = 0; i < 2; i++) {
      int idx = t + i * 256;
      int srow = idx >> 3, sc8 = idx & 7;
      const u16* gk = qkv + (size_t)(b * S + k0 + srow) * HD3 + 1024 + h * 64 + sc8 * 8;
      *(i32x4*)&Klds[srow][sc8 * 8] = *(const i32x4*)gk;
      i32x4 vv = *(const i32x4*)(gk + 1024);
      const u16* ve = (const u16*)&vv;
#pragma unroll
      for (int j = 0; j < 8; j++) Vt[sc8 * 8 + j][srow] = ve[j];
    }
    __syncthreads();

    // S = Q K^T / 8
    f32x4 sf[4];
#pragma unroll
    for (int f = 0; f < 4; f++) {
      f32x4 s = (f32x4){0.f, 0.f, 0.f, 0.f};
      bf16x8 kf0 = *(const bf16x8*)&Klds[f * 16 + r16][g * 8];
      bf16x8 kf1 = *(const bf16x8*)&Klds[f * 16 + r16][32 + g * 8];
      s = __builtin_amdgcn_mfma_f32_16x16x32_bf16(qf0, kf0, s, 0, 0, 0);
      s = __builtin_amdgcn_mfma_f32_16x16x32_bf16(qf1, kf1, s, 0, 0, 0);
      sf[f] = s * 0.125f;
    }
    if (kt == qb) {
#pragma unroll
      for (int f = 0; f < 4; f++)
#pragma unroll
        for (int rr = 0; rr < 4; rr++)
          if (k0 + f * 16 + r16 > q0 + g * 4 + rr) sf[f][rr] = -1e30f;
    }
    // online softmax (rows live across 16-lane groups)
    float tm[4];
#pragma unroll
    for (int rr = 0; rr < 4; rr++)
      tm[rr] = fmaxf(fmaxf(sf[0][rr], sf[1][rr]), fmaxf(sf[2][rr], sf[3][rr]));
#pragma unroll
    for (int m = 8; m; m >>= 1)
#pragma unroll
      for (int rr = 0; rr < 4; rr++) tm[rr] = fmaxf(tm[rr], __shfl_xor(tm[rr], m, 64));

    float psum[4];
#pragma unroll
    for (int rr = 0; rr < 4; rr++) {
      float mnew = fmaxf(mrun[rr], tm[rr]);
      float sc = __expf(mrun[rr] - mnew);
      mrun[rr] = mnew;
      lrun[rr] *= sc;
#pragma unroll
      for (int f = 0; f < 4; f++) ctxa[f][rr] *= sc;
      psum[rr] = 0.f;
    }
#pragma unroll
    for (int f = 0; f < 4; f++)
#pragma unroll
      for (int rr = 0; rr < 4; rr++) {
        float p = __expf(sf[f][rr] - mrun[rr]);
        psum[rr] += p;
        Pbuf[w][g * 4 + rr][f * 16 + r16] = f2bf(p);
      }
#pragma unroll
    for (int m = 8; m; m >>= 1)
#pragma unroll
      for (int rr = 0; rr < 4; rr++) psum[rr] += __shfl_xor(psum[rr], m, 64);
#pragma unroll
    for (int rr = 0; rr < 4; rr++) lrun[rr] += psum[rr];

    // ctx += P V  (P via same-wave LDS transpose, V^T staged in LDS)
    bf16x8 pf0 = *(const bf16x8*)&Pbuf[w][r16][g * 8];
    bf16x8 pf1 = *(const bf16x8*)&Pbuf[w][r16][32 + g * 8];
#pragma unroll
    for (int f = 0; f < 4; f++) {
      bf16x8 v0 = *(const bf16x8*)&Vt[f * 16 + r16][g * 8];
      bf16x8 v1 = *(const bf16x8*)&Vt[f * 16 + r16][32 + g * 8];
      ctxa[f] = __builtin_amdgcn_mfma_f32_16x16x32_bf16(pf0, v0, ctxa[f], 0, 0, 0);
      ctxa[f] = __builtin_amdgcn_mfma_f32_16x16x32_bf16(pf1, v1, ctxa[f], 0, 0, 0);
    }
  }

#pragma unroll
  for (int rr = 0; rr < 4; rr++) {
    float inv = 1.0f / lrun[rr];
    int q = q0 + g * 4 + rr;
#pragma unroll
    for (int f = 0; f < 4; f++) {
      float v = ctxa[f][rr] * inv;
      ctxb[(size_t)(b * S + q) * 1024 + h * 64 + f * 16 + r16] = f2bf(v);
    }
  }
}

// ---------------- in-place LayerNorm over rows of 1024 ----------------------
__global__ __launch_bounds__(256) void ln_kernel(float* __restrict__ y,
                                                 const float* __restrict__ gamma,
                                                 const float* __restrict__ beta) {
  __shared__ float sh[4];
  const int row = blockIdx.x, t = threadIdx.x;
  const int w = t >> 6, l = t & 63;
  float4 v = ((const float4*)(y + (size_t)row * 1024))[t];
  float s = v.x + v.y + v.z + v.w;
#pragma unroll
  for (int m = 32; m; m >>= 1) s += __shfl_xor(s, m, 64);
  if (l == 0) sh[w] = s;
  __syncthreads();
  float mu = (sh[0] + sh[1] + sh[2] + sh[3]) * (1.0f / 1024.0f);
  float dx = v.x - mu, dy = v.y - mu, dz = v.z - mu, dw = v.w - mu;
  float ss = dx * dx + dy * dy + dz * dz + dw * dw;
#pragma unroll
  for (int m = 32; m; m >>= 1) ss += __shfl_xor(ss, m, 64);
  __syncthreads();
  if (l == 0) sh[w] = ss;
  __syncthreads();
  float var = (sh[0] + sh[1] + sh[2] + sh[3]) * (1.0f / 1024.0f);
  float rs = rsqrtf(var + 1e-5f);
  float4 gm = ((const float4*)gamma)[t];
  float4 bt = ((const float4*)beta)[t];
  float4 o;
  o.x = dx * rs * gm.x + bt.x;
  o.y = dy * rs * gm.y + bt.y;
  o.z = dz * rs * gm.z + bt.z;
  o.w = dw * rs * gm.w + bt.w;
  ((float4*)(y + (size_t)row * 1024))[t] = o;
}

// ---------------- launcher ---------------------------------------------------
extern "C" void kernel_launch(void* const* d_in, const int* in_sizes, int n_in,
                              void* d_out, int out_size, void* d_ws, size_t ws_size,
                              hipStream_t stream) {
  (void)in_sizes; (void)n_in; (void)out_size; (void)ws_size;
  const float* x     = (const float*)d_in[0];
  const float* w1    = (const float*)d_in[1];
  const float* b1    = (const float*)d_in[2];
  const float* w2    = (const float*)d_in[3];
  const float* b2    = (const float*)d_in[4];
  const float* gamma = (const float*)d_in[5];
  const float* beta  = (const float*)d_in[6];
  float* out = (float*)d_out;

  const int M = 8192, D = 1024, N1 = 3072;

  char* ws = (char*)d_ws;
  u16* x_bf   = (u16*)(ws);                 // 8192*1024*2  = 16777216
  u16* w1_bf  = (u16*)(ws + 16777216);      // 3072*1024*2  =  6291456
  u16* w2_bf  = (u16*)(ws + 23068672);      // 1024*1024*2  =  2097152
  u16* qkv_bf = (u16*)(ws + 25165824);      // 8192*3072*2  = 50331648
  u16* ctx_bf = (u16*)(ws + 75497472);      // 8192*1024*2  = 16777216

  cvt_kernel<<<2048, 256, 0, stream>>>(x, x_bf, M * D / 4);
  cvt_kernel<<<1024, 256, 0, stream>>>(w1, w1_bf, N1 * D / 4);
  cvt_kernel<<<512, 256, 0, stream>>>(w2, w2_bf, D * D / 4);

  gemm_bt<0><<<dim3(N1 / 128, M / 128), 256, 0, stream>>>(
      x_bf, w1_bf, b1, qkv_bf, nullptr, nullptr, M, N1, D);

  attn_kernel<<<dim3(32, 16, 4), 256, 0, stream>>>(qkv_bf, ctx_bf);

  gemm_bt<1><<<dim3(D / 128, M / 128), 256, 0, stream>>>(
      ctx_bf, w2_bf, b2, nullptr, out, x, M, D, D);

  ln_kernel<<<M, 256, 0, stream>>>(out, gamma, beta);
}

// Round 2
// 321.740 us; speedup vs baseline: 1.6715x; 1.6715x over previous
//
#include <hip/hip_runtime.h>
#include <stdint.h>

typedef unsigned short u16;
typedef __bf16 bf16x8 __attribute__((ext_vector_type(8)));
typedef float  f32x4  __attribute__((ext_vector_type(4)));
typedef int    i32x4  __attribute__((ext_vector_type(4)));

__device__ __forceinline__ u16 f2bf(float f){
  union{float f; uint32_t u;} v; v.f = f;
  uint32_t r = v.u + 0x7FFFu + ((v.u >> 16) & 1u);
  return (u16)(r >> 16);
}

#define GLDS16(gp, lp) __builtin_amdgcn_global_load_lds( \
    (const __attribute__((address_space(1))) void*)(gp),  \
    (__attribute__((address_space(3))) void*)(lp), 16, 0, 0)

// ---------------- fp32 -> bf16 convert (vectorized, grid-stride) ------------
__global__ __launch_bounds__(256) void cvt_kernel(const float* __restrict__ in,
                                                  u16* __restrict__ out, int n4) {
  int stride = gridDim.x * blockDim.x;
  for (int i = blockIdx.x * blockDim.x + threadIdx.x; i < n4; i += stride) {
    float4 v = ((const float4*)in)[i];
    u16 o0 = f2bf(v.x), o1 = f2bf(v.y), o2 = f2bf(v.z), o3 = f2bf(v.w);
    u16* p = out + (size_t)i * 4;
    uint32_t lo = (uint32_t)o0 | ((uint32_t)o1 << 16);
    uint32_t hi = (uint32_t)o2 | ((uint32_t)o3 << 16);
    ((uint2*)p)[0] = make_uint2(lo, hi);
  }
}

// ---------------- bf16 GEMM, C = A * B^T (+bias)(+resid) --------------------
template <int MODE>
__global__ __launch_bounds__(256) void gemm_bt(
    const u16* __restrict__ A, const u16* __restrict__ B,
    const float* __restrict__ bias,
    u16* __restrict__ Cbf, float* __restrict__ Cf, const float* __restrict__ resid,
    int M, int N, int K) {
  __shared__ u16 Alds[128 * 32];
  __shared__ u16 Blds[128 * 32];
  const int t = threadIdx.x;
  const int w = t >> 6, l = t & 63;
  const int wr = w >> 1, wc = w & 1;
  const int g = l >> 4, r16 = l & 15;
  const int brow = blockIdx.y * 128, bcol = blockIdx.x * 128;

  f32x4 acc[4][4];
#pragma unroll
  for (int mi = 0; mi < 4; mi++)
#pragma unroll
    for (int nj = 0; nj < 4; nj++) acc[mi][nj] = (f32x4){0.f, 0.f, 0.f, 0.f};

  const int c0 = 2 * w, c1 = 2 * w + 1;
  const int srow0 = c0 * 16 + (l >> 2);
  const int srow1 = c1 * 16 + (l >> 2);
  const int scol = (l & 3) * 8;

  for (int kt = 0; kt < K; kt += 32) {
    __syncthreads();
    GLDS16(A + (size_t)(brow + srow0) * K + kt + scol, (char*)Alds + c0 * 1024);
    GLDS16(A + (size_t)(brow + srow1) * K + kt + scol, (char*)Alds + c1 * 1024);
    GLDS16(B + (size_t)(bcol + srow0) * K + kt + scol, (char*)Blds + c0 * 1024);
    GLDS16(B + (size_t)(bcol + srow1) * K + kt + scol, (char*)Blds + c1 * 1024);
    __syncthreads();

    bf16x8 af[4], bfr[4];
#pragma unroll
    for (int mi = 0; mi < 4; mi++)
      af[mi] = *(const bf16x8*)&Alds[(wr * 64 + mi * 16 + r16) * 32 + g * 8];
#pragma unroll
    for (int nj = 0; nj < 4; nj++)
      bfr[nj] = *(const bf16x8*)&Blds[(wc * 64 + nj * 16 + r16) * 32 + g * 8];
#pragma unroll
    for (int mi = 0; mi < 4; mi++)
#pragma unroll
      for (int nj = 0; nj < 4; nj++)
        acc[mi][nj] = __builtin_amdgcn_mfma_f32_16x16x32_bf16(af[mi], bfr[nj], acc[mi][nj], 0, 0, 0);
  }

#pragma unroll
  for (int mi = 0; mi < 4; mi++) {
#pragma unroll
    for (int nj = 0; nj < 4; nj++) {
      int col = bcol + wc * 64 + nj * 16 + r16;
      float bv = bias[col];
#pragma unroll
      for (int rr = 0; rr < 4; rr++) {
        int row = brow + wr * 64 + mi * 16 + g * 4 + rr;
        float v = acc[mi][nj][rr] + bv;
        if (MODE == 0) {
          Cbf[(size_t)row * N + col] = f2bf(v);
        } else {
          v += resid[(size_t)row * N + col];
          Cf[(size_t)row * N + col] = v;
        }
      }
    }
  }
}

// ---------------- V transpose: qkv V-part -> vtg[b][h][64d][2048k] ----------
__global__ __launch_bounds__(256) void vtrans_kernel(const u16* __restrict__ qkv,
                                                     u16* __restrict__ vtg) {
  const int S = 2048, HD3 = 3072;
  __shared__ u16 Vs[64 * 64];  // 128B rows, slot^(row&7) swizzled
  const int st = blockIdx.x, h = blockIdx.y, b = blockIdx.z;
  const int t = threadIdx.x;
  const int s0 = st * 64;
#pragma unroll
  for (int i = 0; i < 2; i++) {
    int n = t + i * 256;
    int row = n >> 3, c = n & 7;
    const u16* src = qkv + ((size_t)(b * S) + s0 + row) * HD3 + 2048 + h * 64 + c * 8;
    i32x4 v = *(const i32x4*)src;
    *(i32x4*)&Vs[row * 64 + ((c ^ (row & 7)) << 3)] = v;
  }
  __syncthreads();
  const int d = t >> 2;
  const int dc = d >> 3, dl = d & 7;
#pragma unroll
  for (int i = 0; i < 2; i++) {
    int kc = (t & 3) + i * 4;
    u16 tmp[8];
#pragma unroll
    for (int j = 0; j < 8; j++) {
      int k = kc * 8 + j;
      tmp[j] = Vs[k * 64 + ((dc ^ (k & 7)) << 3) + dl];
    }
    *(i32x4*)(vtg + ((size_t)(b * 16 + h) * 64 + d) * S + s0 + kc * 8) = *(i32x4*)tmp;
  }
}

// ---------------- causal flash attention (swapped QK^T, swizzled LDS) -------
// qkv: [B*S][3072] bf16 (q | k | v). vtg: [b][h][64][2048] bf16 (V^T).
// ctxb: [B*S][1024] bf16 output.
__global__ __launch_bounds__(256) void attn_kernel(const u16* __restrict__ qkv,
                                                   const u16* __restrict__ vtg,
                                                   u16* __restrict__ ctxb) {
  const int S = 2048, HD3 = 3072;
  __shared__ u16 Kl[2][64 * 64];  // rows k, cols hd, swizzled slots
  __shared__ u16 Vl[2][64 * 64];  // rows d, cols k, swizzled slots
  __shared__ u16 Pb[4][16 * 64];  // per-wave: rows q(16), cols k(64), swizzled

  const int qi = 15 - (int)blockIdx.y;
  const int h = blockIdx.x & 15, b = blockIdx.x >> 4;
  const int t = threadIdx.x, w = t >> 6, l = t & 63;
  const int g = l >> 4, r16 = l & 15;
  const int q0 = qi * 128;
  const int nt = 2 * qi + 2;
  const size_t bS = (size_t)b * S;
  const size_t vbase = ((size_t)(b * 16 + h)) * 64 * S;

  // Q fragments: wave handles q rows [q0 + 32w, +32), as two 16-row halves
  const int q0w = q0 + w * 32;
  bf16x8 qf[2][2];
#pragma unroll
  for (int hh = 0; hh < 2; hh++) {
    const u16* qp = qkv + (bS + q0w + hh * 16 + r16) * HD3 + h * 64 + g * 8;
    qf[hh][0] = *(const bf16x8*)qp;
    qf[hh][1] = *(const bf16x8*)(qp + 32);
  }

  f32x4 ctx[2][4];
#pragma unroll
  for (int hh = 0; hh < 2; hh++)
#pragma unroll
    for (int f = 0; f < 4; f++) ctx[hh][f] = (f32x4){0.f, 0.f, 0.f, 0.f};
  float mrun[2] = {-1e30f, -1e30f};
  float lrun[2] = {0.f, 0.f};

  // stage tile kt into buffer bi (K rows + V^T rows), swizzled source cols
#define STAGE(kt_, bi_)                                                        \
  do {                                                                         \
    const int k0s = (kt_) * 64;                                                \
    _Pragma("unroll")                                                          \
    for (int c = 0; c < 2; c++) {                                              \
      int n = c * 256 + t;                                                     \
      int row = n >> 3, sl = n & 7;                                            \
      int col = ((sl ^ (row & 7)) << 3);                                       \
      GLDS16(qkv + (bS + k0s + row) * HD3 + 1024 + h * 64 + col,               \
             (char*)&Kl[bi_][0] + c * 4096 + w * 1024);                        \
      GLDS16(vtg + vbase + (size_t)row * S + k0s + col,                        \
             (char*)&Vl[bi_][0] + c * 4096 + w * 1024);                        \
    }                                                                          \
  } while (0)

  STAGE(0, 0);
  int cur = 0;
  for (int kt = 0; kt < nt; kt++) {
    const int k0 = kt * 64;
    asm volatile("s_waitcnt vmcnt(0)" ::: "memory");
    __syncthreads();
    if (kt + 1 < nt) STAGE(kt + 1, cur ^ 1);

    // K fragments (shared by both q-halves)
    bf16x8 kf[4][2];
#pragma unroll
    for (int f = 0; f < 4; f++) {
      int row = f * 16 + r16;
#pragma unroll
      for (int c = 0; c < 2; c++)
        kf[f][c] = *(const bf16x8*)&Kl[cur][row * 64 + (((c * 4 + g) ^ (row & 7)) << 3)];
    }

#pragma unroll
    for (int hh = 0; hh < 2; hh++) {
      const int qmin = q0w + hh * 16;
      if (k0 >= qmin + 16) continue;  // fully masked (wave-uniform)

      // S^T = (K Q^T)/8 : lane holds S[k = k0+f*16+g*4+rr][q = qmin+r16]
      f32x4 sf[4];
#pragma unroll
      for (int f = 0; f < 4; f++) {
        f32x4 s = (f32x4){0.f, 0.f, 0.f, 0.f};
        s = __builtin_amdgcn_mfma_f32_16x16x32_bf16(kf[f][0], qf[hh][0], s, 0, 0, 0);
        s = __builtin_amdgcn_mfma_f32_16x16x32_bf16(kf[f][1], qf[hh][1], s, 0, 0, 0);
        sf[f] = s * 0.125f;
      }
      const int qg = qmin + r16;
      if (k0 + 64 > qmin) {  // diagonal tile: mask k > q
#pragma unroll
        for (int f = 0; f < 4; f++)
#pragma unroll
          for (int rr = 0; rr < 4; rr++)
            if (k0 + f * 16 + g * 4 + rr > qg) sf[f][rr] = -1e30f;
      }

      // row max: 15 in-lane + 2 shfl (across the 4 lane-groups)
      float tm = sf[0][0];
#pragma unroll
      for (int f = 0; f < 4; f++)
#pragma unroll
        for (int rr = 0; rr < 4; rr++) tm = fmaxf(tm, sf[f][rr]);
      tm = fmaxf(tm, __shfl_xor(tm, 16, 64));
      tm = fmaxf(tm, __shfl_xor(tm, 32, 64));

      float mold = mrun[hh];
      float mnew = fmaxf(mold, tm);
      mrun[hh] = mnew;

      float p[4][4];
      float ps = 0.f;
#pragma unroll
      for (int f = 0; f < 4; f++)
#pragma unroll
        for (int rr = 0; rr < 4; rr++) {
          p[f][rr] = __expf(sf[f][rr] - mnew);
          ps += p[f][rr];
        }
      ps += __shfl_xor(ps, 16, 64);
      ps += __shfl_xor(ps, 32, 64);
      float sc = __expf(mold - mnew);
      lrun[hh] = lrun[hh] * sc + ps;

      // write P^T to per-wave Pb (q-major, swizzled, packed bf16 pairs)
#pragma unroll
      for (int f = 0; f < 4; f++)
#pragma unroll
        for (int rr2 = 0; rr2 < 4; rr2 += 2) {
          union { __bf16 b; u16 u; } a0, a1;
          a0.b = (__bf16)p[f][rr2];
          a1.b = (__bf16)p[f][rr2 + 1];
          uint32_t pk = (uint32_t)a0.u | ((uint32_t)a1.u << 16);
          int kidx = f * 16 + g * 4 + rr2;
          int ch = kidx >> 3;
          *(uint32_t*)((char*)&Pb[w][0] + r16 * 128 + ((ch ^ (r16 & 7)) << 4) +
                       ((kidx & 7) << 1)) = pk;
        }

      // rescale ctx (ctx lanes index q by g*4+rr -> broadcast sc from lane q)
#pragma unroll
      for (int rr = 0; rr < 4; rr++) {
        float scq = __shfl(sc, g * 4 + rr, 64);
#pragma unroll
        for (int f = 0; f < 4; f++) ctx[hh][f][rr] *= scq;
      }

      // PV: ctx[q][d] += P[q][:] V[:][d]
      bf16x8 pf[2];
#pragma unroll
      for (int kh = 0; kh < 2; kh++)
        pf[kh] = *(const bf16x8*)((char*)&Pb[w][0] + r16 * 128 +
                                  (((kh * 4 + g) ^ (r16 & 7)) << 4));
#pragma unroll
      for (int f = 0; f < 4; f++) {
        int row = f * 16 + r16;
#pragma unroll
        for (int kh = 0; kh < 2; kh++) {
          bf16x8 vf = *(const bf16x8*)&Vl[cur][row * 64 + (((kh * 4 + g) ^ (row & 7)) << 3)];
          ctx[hh][f] = __builtin_amdgcn_mfma_f32_16x16x32_bf16(pf[kh], vf, ctx[hh][f], 0, 0, 0);
        }
      }
    }
    cur ^= 1;
  }

  // epilogue: lane holds ctx[q = qmin + g*4+rr][d = f*16 + r16]
#pragma unroll
  for (int hh = 0; hh < 2; hh++) {
    float linv = 1.f / lrun[hh];
#pragma unroll
    for (int rr = 0; rr < 4; rr++) {
      float li = __shfl(linv, g * 4 + rr, 64);
      int qg = q0w + hh * 16 + g * 4 + rr;
#pragma unroll
      for (int f = 0; f < 4; f++) {
        union { __bf16 b; u16 u; } o;
        o.b = (__bf16)(ctx[hh][f][rr] * li);
        ctxb[(bS + qg) * 1024 + h * 64 + f * 16 + r16] = o.u;
      }
    }
  }
#undef STAGE
}

// ---------------- in-place LayerNorm over rows of 1024 ----------------------
__global__ __launch_bounds__(256) void ln_kernel(float* __restrict__ y,
                                                 const float* __restrict__ gamma,
                                                 const float* __restrict__ beta) {
  __shared__ float sh[4];
  const int row = blockIdx.x, t = threadIdx.x;
  const int w = t >> 6, l = t & 63;
  float4 v = ((const float4*)(y + (size_t)row * 1024))[t];
  float s = v.x + v.y + v.z + v.w;
#pragma unroll
  for (int m = 32; m; m >>= 1) s += __shfl_xor(s, m, 64);
  if (l == 0) sh[w] = s;
  __syncthreads();
  float mu = (sh[0] + sh[1] + sh[2] + sh[3]) * (1.0f / 1024.0f);
  float dx = v.x - mu, dy = v.y - mu, dz = v.z - mu, dw = v.w - mu;
  float ss = dx * dx + dy * dy + dz * dz + dw * dw;
#pragma unroll
  for (int m = 32; m; m >>= 1) ss += __shfl_xor(ss, m, 64);
  __syncthreads();
  if (l == 0) sh[w] = ss;
  __syncthreads();
  float var = (sh[0] + sh[1] + sh[2] + sh[3]) * (1.0f / 1024.0f);
  float rs = rsqrtf(var + 1e-5f);
  float4 gm = ((const float4*)gamma)[t];
  float4 bt = ((const float4*)beta)[t];
  float4 o;
  o.x = dx * rs * gm.x + bt.x;
  o.y = dy * rs * gm.y + bt.y;
  o.z = dz * rs * gm.z + bt.z;
  o.w = dw * rs * gm.w + bt.w;
  ((float4*)(y + (size_t)row * 1024))[t] = o;
}

// ---------------- launcher ---------------------------------------------------
extern "C" void kernel_launch(void* const* d_in, const int* in_sizes, int n_in,
                              void* d_out, int out_size, void* d_ws, size_t ws_size,
                              hipStream_t stream) {
  (void)in_sizes; (void)n_in; (void)out_size; (void)ws_size;
  const float* x     = (const float*)d_in[0];
  const float* w1    = (const float*)d_in[1];
  const float* b1    = (const float*)d_in[2];
  const float* w2    = (const float*)d_in[3];
  const float* b2    = (const float*)d_in[4];
  const float* gamma = (const float*)d_in[5];
  const float* beta  = (const float*)d_in[6];
  float* out = (float*)d_out;

  const int M = 8192, D = 1024, N1 = 3072;

  char* ws = (char*)d_ws;
  u16* x_bf   = (u16*)(ws);                 // 16 MB; dead after gemm1
  u16* w1_bf  = (u16*)(ws + 16777216);
  u16* w2_bf  = (u16*)(ws + 23068672);
  u16* qkv_bf = (u16*)(ws + 25165824);      // 50 MB
  u16* ctx_bf = (u16*)(ws + 75497472);      // 16 MB
  u16* vtg    = (u16*)(ws);                 // reuses x_bf region (16 MB)

  cvt_kernel<<<2048, 256, 0, stream>>>(x, x_bf, M * D / 4);
  cvt_kernel<<<1024, 256, 0, stream>>>(w1, w1_bf, N1 * D / 4);
  cvt_kernel<<<512, 256, 0, stream>>>(w2, w2_bf, D * D / 4);

  gemm_bt<0><<<dim3(N1 / 128, M / 128), 256, 0, stream>>>(
      x_bf, w1_bf, b1, qkv_bf, nullptr, nullptr, M, N1, D);

  vtrans_kernel<<<dim3(32, 16, 4), 256, 0, stream>>>(qkv_bf, vtg);

  // grid: x = b*16+h (64), y = qi reversed (16) -> longest blocks dispatch first
  attn_kernel<<<dim3(64, 16), 256, 0, stream>>>(qkv_bf, vtg, ctx_bf);

  gemm_bt<1><<<dim3(D / 128, M / 128), 256, 0, stream>>>(
      ctx_bf, w2_bf, b2, nullptr, out, x, M, D, D);

  ln_kernel<<<M, 256, 0, stream>>>(out, gamma, beta);
}

// Round 3
// 318.645 us; speedup vs baseline: 1.6878x; 1.0097x over previous
//
#include <hip/hip_runtime.h>
#include <stdint.h>

typedef unsigned short u16;
typedef __bf16 bf16x8 __attribute__((ext_vector_type(8)));
typedef float  f32x4  __attribute__((ext_vector_type(4)));
typedef int    i32x4  __attribute__((ext_vector_type(4)));

__device__ __forceinline__ u16 f2bf(float f){
  union{float f; uint32_t u;} v; v.f = f;
  uint32_t r = v.u + 0x7FFFu + ((v.u >> 16) & 1u);
  return (u16)(r >> 16);
}

#define GLDS16(gp, lp) __builtin_amdgcn_global_load_lds( \
    (const __attribute__((address_space(1))) void*)(gp),  \
    (__attribute__((address_space(3))) void*)(lp), 16, 0, 0)

// ---------------- fp32 -> bf16 convert (vectorized, grid-stride) ------------
__global__ __launch_bounds__(256) void cvt_kernel(const float* __restrict__ in,
                                                  u16* __restrict__ out, int n4) {
  int stride = gridDim.x * blockDim.x;
  for (int i = blockIdx.x * blockDim.x + threadIdx.x; i < n4; i += stride) {
    float4 v = ((const float4*)in)[i];
    u16 o0 = f2bf(v.x), o1 = f2bf(v.y), o2 = f2bf(v.z), o3 = f2bf(v.w);
    u16* p = out + (size_t)i * 4;
    uint32_t lo = (uint32_t)o0 | ((uint32_t)o1 << 16);
    uint32_t hi = (uint32_t)o2 | ((uint32_t)o3 << 16);
    ((uint2*)p)[0] = make_uint2(lo, hi);
  }
}

// ---------------- bf16 GEMM, C = A * B^T (+bias)(+resid) --------------------
template <int MODE>
__global__ __launch_bounds__(256) void gemm_bt(
    const u16* __restrict__ A, const u16* __restrict__ B,
    const float* __restrict__ bias,
    u16* __restrict__ Cbf, float* __restrict__ Cf, const float* __restrict__ resid,
    int M, int N, int K) {
  __shared__ u16 Alds[128 * 32];
  __shared__ u16 Blds[128 * 32];
  const int t = threadIdx.x;
  const int w = t >> 6, l = t & 63;
  const int wr = w >> 1, wc = w & 1;
  const int g = l >> 4, r16 = l & 15;

  // bijective XCD swizzle: contiguous grid chunk per XCD (nwg % 8 == 0)
  const int gx = gridDim.x;
  const int nwg = gx * gridDim.y;
  const int wg = blockIdx.y * gx + blockIdx.x;
  const int cpx = nwg >> 3;
  const int swz = (wg & 7) * cpx + (wg >> 3);
  const int brow = (swz / gx) * 128, bcol = (swz % gx) * 128;

  f32x4 acc[4][4];
#pragma unroll
  for (int mi = 0; mi < 4; mi++)
#pragma unroll
    for (int nj = 0; nj < 4; nj++) acc[mi][nj] = (f32x4){0.f, 0.f, 0.f, 0.f};

  const int c0 = 2 * w, c1 = 2 * w + 1;
  const int srow0 = c0 * 16 + (l >> 2);
  const int srow1 = c1 * 16 + (l >> 2);
  const int scol = (l & 3) * 8;

  for (int kt = 0; kt < K; kt += 32) {
    __syncthreads();
    GLDS16(A + (size_t)(brow + srow0) * K + kt + scol, (char*)Alds + c0 * 1024);
    GLDS16(A + (size_t)(brow + srow1) * K + kt + scol, (char*)Alds + c1 * 1024);
    GLDS16(B + (size_t)(bcol + srow0) * K + kt + scol, (char*)Blds + c0 * 1024);
    GLDS16(B + (size_t)(bcol + srow1) * K + kt + scol, (char*)Blds + c1 * 1024);
    __syncthreads();

    bf16x8 af[4], bfr[4];
#pragma unroll
    for (int mi = 0; mi < 4; mi++)
      af[mi] = *(const bf16x8*)&Alds[(wr * 64 + mi * 16 + r16) * 32 + g * 8];
#pragma unroll
    for (int nj = 0; nj < 4; nj++)
      bfr[nj] = *(const bf16x8*)&Blds[(wc * 64 + nj * 16 + r16) * 32 + g * 8];
#pragma unroll
    for (int mi = 0; mi < 4; mi++)
#pragma unroll
      for (int nj = 0; nj < 4; nj++)
        acc[mi][nj] = __builtin_amdgcn_mfma_f32_16x16x32_bf16(af[mi], bfr[nj], acc[mi][nj], 0, 0, 0);
  }

#pragma unroll
  for (int mi = 0; mi < 4; mi++) {
#pragma unroll
    for (int nj = 0; nj < 4; nj++) {
      int col = bcol + wc * 64 + nj * 16 + r16;
      float bv = bias[col];
#pragma unroll
      for (int rr = 0; rr < 4; rr++) {
        int row = brow + wr * 64 + mi * 16 + g * 4 + rr;
        float v = acc[mi][nj][rr] + bv;
        if (MODE == 0) {
          Cbf[(size_t)row * N + col] = f2bf(v);
        } else {
          v += resid[(size_t)row * N + col];
          Cf[(size_t)row * N + col] = v;
        }
      }
    }
  }
}

// ---------------- V transpose: qkv V-part -> vtg[b][h][64d][2048k] ----------
__global__ __launch_bounds__(256) void vtrans_kernel(const u16* __restrict__ qkv,
                                                     u16* __restrict__ vtg) {
  const int S = 2048, HD3 = 3072;
  __shared__ u16 Vs[64 * 64];
  const int st = blockIdx.x, h = blockIdx.y, b = blockIdx.z;
  const int t = threadIdx.x;
  const int s0 = st * 64;
#pragma unroll
  for (int i = 0; i < 2; i++) {
    int n = t + i * 256;
    int row = n >> 3, c = n & 7;
    const u16* src = qkv + ((size_t)(b * S) + s0 + row) * HD3 + 2048 + h * 64 + c * 8;
    i32x4 v = *(const i32x4*)src;
    *(i32x4*)&Vs[row * 64 + ((c ^ (row & 7)) << 3)] = v;
  }
  __syncthreads();
  const int d = t >> 2;
  const int dc = d >> 3, dl = d & 7;
#pragma unroll
  for (int i = 0; i < 2; i++) {
    int kc = (t & 3) + i * 4;
    u16 tmp[8];
#pragma unroll
    for (int j = 0; j < 8; j++) {
      int k = kc * 8 + j;
      tmp[j] = Vs[k * 64 + ((dc ^ (k & 7)) << 3) + dl];
    }
    *(i32x4*)(vtg + ((size_t)(b * 16 + h) * 64 + d) * S + s0 + kc * 8) = *(i32x4*)tmp;
  }
}

// ---------------- causal flash attention (paired q-tiles, defer-max) --------
// qkv: [B*S][3072] bf16. vtg: [b][h][64][2048] bf16 (V^T). ctxb: bf16 out.
__global__ __launch_bounds__(256) void attn_kernel(const u16* __restrict__ qkv,
                                                   const u16* __restrict__ vtg,
                                                   u16* __restrict__ ctxb) {
  const int S = 2048, HD3 = 3072;
  __shared__ u16 Kl[2][64 * 64];
  __shared__ u16 Vl[2][64 * 64];
  __shared__ u16 Pb[4][16 * 64];

  const int h = blockIdx.x & 15, b = blockIdx.x >> 4;
  const int pair = blockIdx.y;  // 0..7 ; segments qi = pair, 15-pair (34 tiles)
  const int t = threadIdx.x, w = t >> 6, l = t & 63;
  const int g = l >> 4, r16 = l & 15;
  const size_t bS = (size_t)b * S;
  const size_t vbase = ((size_t)(b * 16 + h)) * 64 * S;

  // staging constants: thread covers rows srow / srow+32, swizzled col
  const int srow = t >> 3, ssl = t & 7;
  const int scol = ((ssl ^ (srow & 7)) << 3);  // (srow+32)&7 == srow&7
  const int sdst = w * 1024;                   // wave-uniform LDS dest

  // hoisted LDS byte offsets (shared by K and V reads: same pattern)
  int kfo[4][2], pwo[4][2], pro[2];
#pragma unroll
  for (int f = 0; f < 4; f++) {
    int row = f * 16 + r16;
#pragma unroll
    for (int c = 0; c < 2; c++)
      kfo[f][c] = (row * 64 + (((c * 4 + g) ^ (row & 7)) << 3)) * 2;
#pragma unroll
    for (int q2 = 0; q2 < 2; q2++) {
      int kidx = f * 16 + g * 4 + q2 * 2;
      pwo[f][q2] = r16 * 128 + (((kidx >> 3) ^ (r16 & 7)) << 4) + ((kidx & 7) << 1);
    }
  }
#pragma unroll
  for (int kh = 0; kh < 2; kh++)
    pro[kh] = r16 * 128 + (((kh * 4 + g) ^ (r16 & 7)) << 4);

  const float QSC = 0.125f * 1.44269504f;  // scores in log2 units

#define STAGE(bi_)                                                            \
  do {                                                                        \
    GLDS16(kp, (char*)Kl + (bi_)*8192 + sdst);                                \
    GLDS16(kp + 32 * HD3, (char*)Kl + (bi_)*8192 + 4096 + sdst);              \
    GLDS16(vp, (char*)Vl + (bi_)*8192 + sdst);                                \
    GLDS16(vp + 32 * S, (char*)Vl + (bi_)*8192 + 4096 + sdst);                \
    kp += 64 * HD3; vp += 64;                                                 \
  } while (0)

  for (int seg = 0; seg < 2; seg++) {
    const int qi = seg ? (15 - pair) : pair;
    const int q0w = qi * 128 + w * 32;
    const int nt = 2 * qi + 2;

    // Q fragments, pre-scaled into log2 domain
    bf16x8 qf[2][2];
#pragma unroll
    for (int hh = 0; hh < 2; hh++) {
      const u16* qp = qkv + (bS + q0w + hh * 16 + r16) * HD3 + h * 64 + g * 8;
      bf16x8 a = *(const bf16x8*)qp;
      bf16x8 c = *(const bf16x8*)(qp + 32);
#pragma unroll
      for (int j = 0; j < 8; j++) {
        a[j] = (__bf16)((float)a[j] * QSC);
        c[j] = (__bf16)((float)c[j] * QSC);
      }
      qf[hh][0] = a; qf[hh][1] = c;
    }

    f32x4 ctx[2][4];
#pragma unroll
    for (int hh = 0; hh < 2; hh++)
#pragma unroll
      for (int f = 0; f < 4; f++) ctx[hh][f] = (f32x4){0.f, 0.f, 0.f, 0.f};
    float mrun[2] = {-1e30f, -1e30f};
    float lrun[2] = {0.f, 0.f};

    const u16* kp = qkv + (bS + srow) * HD3 + 1024 + h * 64 + scol;
    const u16* vp = vtg + vbase + (size_t)srow * S + scol;

    __syncthreads();  // previous segment's readers done before overwriting LDS
    STAGE(0);
    int cur = 0;
    for (int kt = 0; kt < nt; kt++) {
      const int k0 = kt * 64;
      asm volatile("s_waitcnt vmcnt(0)" ::: "memory");
      __syncthreads();
      if (kt + 1 < nt) STAGE(cur ^ 1);

      const char* KB = (const char*)Kl + cur * 8192;
      const char* VB = (const char*)Vl + cur * 8192;
      bf16x8 kf[4][2];
#pragma unroll
      for (int f = 0; f < 4; f++)
#pragma unroll
        for (int c = 0; c < 2; c++) kf[f][c] = *(const bf16x8*)(KB + kfo[f][c]);

#pragma unroll
      for (int hh = 0; hh < 2; hh++) {
        const int qmin = q0w + hh * 16;
        if (k0 >= qmin + 16) continue;

        // S^T (log2 units): lane holds S[k0+f*16+g*4+rr][qmin+r16]
        f32x4 sf[4];
#pragma unroll
        for (int f = 0; f < 4; f++) {
          f32x4 s = (f32x4){0.f, 0.f, 0.f, 0.f};
          s = __builtin_amdgcn_mfma_f32_16x16x32_bf16(kf[f][0], qf[hh][0], s, 0, 0, 0);
          s = __builtin_amdgcn_mfma_f32_16x16x32_bf16(kf[f][1], qf[hh][1], s, 0, 0, 0);
          sf[f] = s;
        }
        const int qg = qmin + r16;
        if (k0 + 64 > qmin) {
#pragma unroll
          for (int f = 0; f < 4; f++)
#pragma unroll
            for (int rr = 0; rr < 4; rr++)
              if (k0 + f * 16 + g * 4 + rr > qg) sf[f][rr] = -1e30f;
        }

        float tm = sf[0][0];
#pragma unroll
        for (int f = 0; f < 4; f++)
#pragma unroll
          for (int rr = 0; rr < 4; rr++) tm = fmaxf(tm, sf[f][rr]);
        tm = fmaxf(tm, __shfl_xor(tm, 16, 64));
        tm = fmaxf(tm, __shfl_xor(tm, 32, 64));

        const float mold = mrun[hh];
        const bool skip = __all(tm <= mold + 8.0f);  // defer-max (log2 THR=8)
        const float mnew = skip ? mold : fmaxf(mold, tm);
        mrun[hh] = mnew;

        float p[4][4];
        float ps = 0.f;
#pragma unroll
        for (int f = 0; f < 4; f++)
#pragma unroll
          for (int rr = 0; rr < 4; rr++) {
            p[f][rr] = exp2f(sf[f][rr] - mnew);
            ps += p[f][rr];
          }
        ps += __shfl_xor(ps, 16, 64);
        ps += __shfl_xor(ps, 32, 64);

        if (skip) {
          lrun[hh] += ps;
        } else {
          float sc = exp2f(mold - mnew);
          lrun[hh] = lrun[hh] * sc + ps;
#pragma unroll
          for (int rr = 0; rr < 4; rr++) {
            float scq = __shfl(sc, g * 4 + rr, 64);
#pragma unroll
            for (int f = 0; f < 4; f++) ctx[hh][f][rr] *= scq;
          }
        }

        // P^T -> per-wave swizzled Pb (packed bf16 pairs)
        char* PW = (char*)Pb + w * 2048;
#pragma unroll
        for (int f = 0; f < 4; f++)
#pragma unroll
          for (int q2 = 0; q2 < 2; q2++) {
            union { __bf16 b; u16 u; } a0, a1;
            a0.b = (__bf16)p[f][q2 * 2];
            a1.b = (__bf16)p[f][q2 * 2 + 1];
            *(uint32_t*)(PW + pwo[f][q2]) = (uint32_t)a0.u | ((uint32_t)a1.u << 16);
          }

        bf16x8 pf[2];
#pragma unroll
        for (int kh = 0; kh < 2; kh++) pf[kh] = *(const bf16x8*)(PW + pro[kh]);
#pragma unroll
        for (int f = 0; f < 4; f++)
#pragma unroll
          for (int kh = 0; kh < 2; kh++) {
            bf16x8 vf = *(const bf16x8*)(VB + kfo[f][kh]);
            ctx[hh][f] = __builtin_amdgcn_mfma_f32_16x16x32_bf16(pf[kh], vf, ctx[hh][f], 0, 0, 0);
          }
      }
      cur ^= 1;
    }

    // epilogue: lane holds ctx[q=qmin+g*4+rr][d=f*16+r16]
#pragma unroll
    for (int hh = 0; hh < 2; hh++) {
      float linv = 1.f / lrun[hh];
#pragma unroll
      for (int rr = 0; rr < 4; rr++) {
        float li = __shfl(linv, g * 4 + rr, 64);
        int qg = q0w + hh * 16 + g * 4 + rr;
#pragma unroll
        for (int f = 0; f < 4; f++) {
          union { __bf16 b; u16 u; } o;
          o.b = (__bf16)(ctx[hh][f][rr] * li);
          ctxb[(bS + qg) * 1024 + h * 64 + f * 16 + r16] = o.u;
        }
      }
    }
  }
#undef STAGE
}

// ---------------- in-place LayerNorm over rows of 1024 ----------------------
__global__ __launch_bounds__(256) void ln_kernel(float* __restrict__ y,
                                                 const float* __restrict__ gamma,
                                                 const float* __restrict__ beta) {
  __shared__ float sh[4];
  const int row = blockIdx.x, t = threadIdx.x;
  const int w = t >> 6, l = t & 63;
  float4 v = ((const float4*)(y + (size_t)row * 1024))[t];
  float s = v.x + v.y + v.z + v.w;
#pragma unroll
  for (int m = 32; m; m >>= 1) s += __shfl_xor(s, m, 64);
  if (l == 0) sh[w] = s;
  __syncthreads();
  float mu = (sh[0] + sh[1] + sh[2] + sh[3]) * (1.0f / 1024.0f);
  float dx = v.x - mu, dy = v.y - mu, dz = v.z - mu, dw = v.w - mu;
  float ss = dx * dx + dy * dy + dz * dz + dw * dw;
#pragma unroll
  for (int m = 32; m; m >>= 1) ss += __shfl_xor(ss, m, 64);
  __syncthreads();
  if (l == 0) sh[w] = ss;
  __syncthreads();
  float var = (sh[0] + sh[1] + sh[2] + sh[3]) * (1.0f / 1024.0f);
  float rs = rsqrtf(var + 1e-5f);
  float4 gm = ((const float4*)gamma)[t];
  float4 bt = ((const float4*)beta)[t];
  float4 o;
  o.x = dx * rs * gm.x + bt.x;
  o.y = dy * rs * gm.y + bt.y;
  o.z = dz * rs * gm.z + bt.z;
  o.w = dw * rs * gm.w + bt.w;
  ((float4*)(y + (size_t)row * 1024))[t] = o;
}

// ---------------- launcher ---------------------------------------------------
extern "C" void kernel_launch(void* const* d_in, const int* in_sizes, int n_in,
                              void* d_out, int out_size, void* d_ws, size_t ws_size,
                              hipStream_t stream) {
  (void)in_sizes; (void)n_in; (void)out_size; (void)ws_size;
  const float* x     = (const float*)d_in[0];
  const float* w1    = (const float*)d_in[1];
  const float* b1    = (const float*)d_in[2];
  const float* w2    = (const float*)d_in[3];
  const float* b2    = (const float*)d_in[4];
  const float* gamma = (const float*)d_in[5];
  const float* beta  = (const float*)d_in[6];
  float* out = (float*)d_out;

  const int M = 8192, D = 1024, N1 = 3072;

  char* ws = (char*)d_ws;
  u16* x_bf   = (u16*)(ws);                 // 16 MB; dead after gemm1
  u16* w1_bf  = (u16*)(ws + 16777216);
  u16* w2_bf  = (u16*)(ws + 23068672);
  u16* qkv_bf = (u16*)(ws + 25165824);      // 50 MB
  u16* ctx_bf = (u16*)(ws + 75497472);      // 16 MB
  u16* vtg    = (u16*)(ws);                 // reuses x_bf region (16 MB)

  cvt_kernel<<<2048, 256, 0, stream>>>(x, x_bf, M * D / 4);
  cvt_kernel<<<1024, 256, 0, stream>>>(w1, w1_bf, N1 * D / 4);
  cvt_kernel<<<512, 256, 0, stream>>>(w2, w2_bf, D * D / 4);

  gemm_bt<0><<<dim3(N1 / 128, M / 128), 256, 0, stream>>>(
      x_bf, w1_bf, b1, qkv_bf, nullptr, nullptr, M, N1, D);

  vtrans_kernel<<<dim3(32, 16, 4), 256, 0, stream>>>(qkv_bf, vtg);

  // grid: x = b*16+h (64), y = pair (8); wg%8 == bh%8 -> same-bh same-XCD
  attn_kernel<<<dim3(64, 8), 256, 0, stream>>>(qkv_bf, vtg, ctx_bf);

  gemm_bt<1><<<dim3(D / 128, M / 128), 256, 0, stream>>>(
      ctx_bf, w2_bf, b2, nullptr, out, x, M, D, D);

  ln_kernel<<<M, 256, 0, stream>>>(out, gamma, beta);
}

// Round 4
// 305.142 us; speedup vs baseline: 1.7625x; 1.0442x over previous
//
#include <hip/hip_runtime.h>
#include <stdint.h>

typedef unsigned short u16;
typedef __bf16 bf16x8 __attribute__((ext_vector_type(8)));
typedef float  f32x4  __attribute__((ext_vector_type(4)));
typedef int    i32x4  __attribute__((ext_vector_type(4)));

__device__ __forceinline__ u16 f2bf(float f){
  union{float f; uint32_t u;} v; v.f = f;
  uint32_t r = v.u + 0x7FFFu + ((v.u >> 16) & 1u);
  return (u16)(r >> 16);
}

#define GLDS16(gp, lp) __builtin_amdgcn_global_load_lds( \
    (const __attribute__((address_space(1))) void*)(gp),  \
    (__attribute__((address_space(3))) void*)(lp), 16, 0, 0)

// ---------------- fp32 -> bf16 convert (vectorized, grid-stride) ------------
__global__ __launch_bounds__(256) void cvt_kernel(const float* __restrict__ in,
                                                  u16* __restrict__ out, int n4) {
  int stride = gridDim.x * blockDim.x;
  for (int i = blockIdx.x * blockDim.x + threadIdx.x; i < n4; i += stride) {
    float4 v = ((const float4*)in)[i];
    u16 o0 = f2bf(v.x), o1 = f2bf(v.y), o2 = f2bf(v.z), o3 = f2bf(v.w);
    u16* p = out + (size_t)i * 4;
    uint32_t lo = (uint32_t)o0 | ((uint32_t)o1 << 16);
    uint32_t hi = (uint32_t)o2 | ((uint32_t)o3 << 16);
    ((uint2*)p)[0] = make_uint2(lo, hi);
  }
}

// ---------------- bf16 GEMM, C = A * B^T (+bias)(+resid) --------------------
template <int MODE>
__global__ __launch_bounds__(256) void gemm_bt(
    const u16* __restrict__ A, const u16* __restrict__ B,
    const float* __restrict__ bias,
    u16* __restrict__ Cbf, float* __restrict__ Cf, const float* __restrict__ resid,
    int M, int N, int K) {
  __shared__ u16 Alds[128 * 32];
  __shared__ u16 Blds[128 * 32];
  const int t = threadIdx.x;
  const int w = t >> 6, l = t & 63;
  const int wr = w >> 1, wc = w & 1;
  const int g = l >> 4, r16 = l & 15;

  // bijective XCD swizzle: contiguous grid chunk per XCD (nwg % 8 == 0)
  const int gx = gridDim.x;
  const int nwg = gx * gridDim.y;
  const int wg = blockIdx.y * gx + blockIdx.x;
  const int cpx = nwg >> 3;
  const int swz = (wg & 7) * cpx + (wg >> 3);
  const int brow = (swz / gx) * 128, bcol = (swz % gx) * 128;

  f32x4 acc[4][4];
#pragma unroll
  for (int mi = 0; mi < 4; mi++)
#pragma unroll
    for (int nj = 0; nj < 4; nj++) acc[mi][nj] = (f32x4){0.f, 0.f, 0.f, 0.f};

  const int c0 = 2 * w, c1 = 2 * w + 1;
  const int srow0 = c0 * 16 + (l >> 2);
  const int srow1 = c1 * 16 + (l >> 2);
  const int scol = (l & 3) * 8;

  for (int kt = 0; kt < K; kt += 32) {
    __syncthreads();
    GLDS16(A + (size_t)(brow + srow0) * K + kt + scol, (char*)Alds + c0 * 1024);
    GLDS16(A + (size_t)(brow + srow1) * K + kt + scol, (char*)Alds + c1 * 1024);
    GLDS16(B + (size_t)(bcol + srow0) * K + kt + scol, (char*)Blds + c0 * 1024);
    GLDS16(B + (size_t)(bcol + srow1) * K + kt + scol, (char*)Blds + c1 * 1024);
    __syncthreads();

    bf16x8 af[4], bfr[4];
#pragma unroll
    for (int mi = 0; mi < 4; mi++)
      af[mi] = *(const bf16x8*)&Alds[(wr * 64 + mi * 16 + r16) * 32 + g * 8];
#pragma unroll
    for (int nj = 0; nj < 4; nj++)
      bfr[nj] = *(const bf16x8*)&Blds[(wc * 64 + nj * 16 + r16) * 32 + g * 8];
#pragma unroll
    for (int mi = 0; mi < 4; mi++)
#pragma unroll
      for (int nj = 0; nj < 4; nj++)
        acc[mi][nj] = __builtin_amdgcn_mfma_f32_16x16x32_bf16(af[mi], bfr[nj], acc[mi][nj], 0, 0, 0);
  }

#pragma unroll
  for (int mi = 0; mi < 4; mi++) {
#pragma unroll
    for (int nj = 0; nj < 4; nj++) {
      int col = bcol + wc * 64 + nj * 16 + r16;
      float bv = bias[col];
#pragma unroll
      for (int rr = 0; rr < 4; rr++) {
        int row = brow + wr * 64 + mi * 16 + g * 4 + rr;
        float v = acc[mi][nj][rr] + bv;
        if (MODE == 0) {
          Cbf[(size_t)row * N + col] = f2bf(v);
        } else {
          v += resid[(size_t)row * N + col];
          Cf[(size_t)row * N + col] = v;
        }
      }
    }
  }
}

// ---------------- V transpose: qkv V-part -> vtg[b][h][64d][2048k] ----------
__global__ __launch_bounds__(256) void vtrans_kernel(const u16* __restrict__ qkv,
                                                     u16* __restrict__ vtg) {
  const int S = 2048, HD3 = 3072;
  __shared__ u16 Vs[64 * 64];
  const int st = blockIdx.x, h = blockIdx.y, b = blockIdx.z;
  const int t = threadIdx.x;
  const int s0 = st * 64;
#pragma unroll
  for (int i = 0; i < 2; i++) {
    int n = t + i * 256;
    int row = n >> 3, c = n & 7;
    const u16* src = qkv + ((size_t)(b * S) + s0 + row) * HD3 + 2048 + h * 64 + c * 8;
    i32x4 v = *(const i32x4*)src;
    *(i32x4*)&Vs[row * 64 + ((c ^ (row & 7)) << 3)] = v;
  }
  __syncthreads();
  const int d = t >> 2;
  const int dc = d >> 3, dl = d & 7;
#pragma unroll
  for (int i = 0; i < 2; i++) {
    int kc = (t & 3) + i * 4;
    u16 tmp[8];
#pragma unroll
    for (int j = 0; j < 8; j++) {
      int k = kc * 8 + j;
      tmp[j] = Vs[k * 64 + ((dc ^ (k & 7)) << 3) + dl];
    }
    *(i32x4*)(vtg + ((size_t)(b * 16 + h) * 64 + d) * S + s0 + kc * 8) = *(i32x4*)tmp;
  }
}

// ---------------- causal flash attention: 8 waves, 16 q-rows/wave -----------
// qkv: [B*S][3072] bf16. vtg: [b][h][64][2048] bf16 (V^T). ctxb: bf16 out.
__global__ __launch_bounds__(512) void attn_kernel(const u16* __restrict__ qkv,
                                                   const u16* __restrict__ vtg,
                                                   u16* __restrict__ ctxb) {
  const int S = 2048, HD3 = 3072;
  __shared__ u16 Kl[2][64 * 64];   // 16 KB
  __shared__ u16 Vl[2][64 * 64];   // 16 KB
  __shared__ u16 Pb[8][16 * 64];   // 16 KB (per-wave P buffer)

  const int h = blockIdx.x & 15, b = blockIdx.x >> 4;
  const int pair = blockIdx.y;  // segments qi = pair, 15-pair (34 tiles total)
  const int t = threadIdx.x, w = t >> 6, l = t & 63;
  const int g = l >> 4, r16 = l & 15;
  const size_t bS = (size_t)b * S;
  const size_t vbase = ((size_t)(b * 16 + h)) * 64 * S;

  // staging: 512 threads cover 64 rows x 8 swizzled 16B slots (one full tile)
  const int srow = t >> 3, ssl = t & 7;
  const int scol = ((ssl ^ (srow & 7)) << 3);
  const int sdst = w * 1024;  // wave-uniform LDS dest; lane offset = l*16

  // hoisted LDS byte offsets (K/V fragment reads share the same pattern)
  int kfo[4][2], pwo[4][2], pro[2];
#pragma unroll
  for (int f = 0; f < 4; f++) {
    int row = f * 16 + r16;
#pragma unroll
    for (int c = 0; c < 2; c++)
      kfo[f][c] = (row * 64 + (((c * 4 + g) ^ (row & 7)) << 3)) * 2;
#pragma unroll
    for (int q2 = 0; q2 < 2; q2++) {
      int kidx = f * 16 + g * 4 + q2 * 2;
      pwo[f][q2] = r16 * 128 + (((kidx >> 3) ^ (r16 & 7)) << 4) + ((kidx & 7) << 1);
    }
  }
#pragma unroll
  for (int kh = 0; kh < 2; kh++)
    pro[kh] = r16 * 128 + (((kh * 4 + g) ^ (r16 & 7)) << 4);

  const float QSC = 0.125f * 1.44269504f;  // scores in log2 units
  char* PW = (char*)Pb + w * 2048;

#define STAGE(bi_)                                                            \
  do {                                                                        \
    GLDS16(kp, (char*)Kl + (bi_)*8192 + sdst);                                \
    GLDS16(vp, (char*)Vl + (bi_)*8192 + sdst);                                \
    kp += 64 * HD3; vp += 64;                                                 \
  } while (0)

  for (int seg = 0; seg < 2; seg++) {
    const int qi = seg ? (15 - pair) : pair;
    const int qmin = qi * 128 + w * 16;  // this wave's 16 q-rows
    const int nt = 2 * qi + 2;

    // Q fragments, pre-scaled into log2 domain
    const u16* qp = qkv + (bS + qmin + r16) * HD3 + h * 64 + g * 8;
    bf16x8 qf0 = *(const bf16x8*)qp;
    bf16x8 qf1 = *(const bf16x8*)(qp + 32);
#pragma unroll
    for (int j = 0; j < 8; j++) {
      qf0[j] = (__bf16)((float)qf0[j] * QSC);
      qf1[j] = (__bf16)((float)qf1[j] * QSC);
    }

    f32x4 ctx[4];
#pragma unroll
    for (int f = 0; f < 4; f++) ctx[f] = (f32x4){0.f, 0.f, 0.f, 0.f};
    float mrun = -1e30f, lrun = 0.f;

    const u16* kp = qkv + (bS + srow) * HD3 + 1024 + h * 64 + scol;
    const u16* vp = vtg + vbase + (size_t)srow * S + scol;

    __syncthreads();  // previous segment's readers done before LDS overwrite
    STAGE(0);
    int cur = 0;
    for (int kt = 0; kt < nt; kt++) {
      const int k0 = kt * 64;
      asm volatile("s_waitcnt vmcnt(0)" ::: "memory");
      __syncthreads();
      if (kt + 1 < nt) STAGE(cur ^ 1);

      if (k0 < qmin + 16) {  // wave participates in this tile
        const char* KB = (const char*)Kl + cur * 8192;
        const char* VB = (const char*)Vl + cur * 8192;

        // S^T (log2 units): lane holds S[k0+f*16+g*4+rr][qmin+r16]
        f32x4 sf[4];
        __builtin_amdgcn_s_setprio(1);
#pragma unroll
        for (int f = 0; f < 4; f++) {
          bf16x8 k0f = *(const bf16x8*)(KB + kfo[f][0]);
          bf16x8 k1f = *(const bf16x8*)(KB + kfo[f][1]);
          f32x4 s = (f32x4){0.f, 0.f, 0.f, 0.f};
          s = __builtin_amdgcn_mfma_f32_16x16x32_bf16(k0f, qf0, s, 0, 0, 0);
          s = __builtin_amdgcn_mfma_f32_16x16x32_bf16(k1f, qf1, s, 0, 0, 0);
          sf[f] = s;
        }
        __builtin_amdgcn_s_setprio(0);

        const int qg = qmin + r16;
        if (k0 + 64 > qmin) {  // diagonal tile: mask k > q
#pragma unroll
          for (int f = 0; f < 4; f++)
#pragma unroll
            for (int rr = 0; rr < 4; rr++)
              if (k0 + f * 16 + g * 4 + rr > qg) sf[f][rr] = -1e30f;
        }

        float tm = sf[0][0];
#pragma unroll
        for (int f = 0; f < 4; f++)
#pragma unroll
          for (int rr = 0; rr < 4; rr++) tm = fmaxf(tm, sf[f][rr]);
        tm = fmaxf(tm, __shfl_xor(tm, 16, 64));
        tm = fmaxf(tm, __shfl_xor(tm, 32, 64));

        const float mold = mrun;
        const bool skip = __all(tm <= mold + 8.0f);  // defer-max (log2 THR=8)
        const float mnew = skip ? mold : fmaxf(mold, tm);
        mrun = mnew;

        float p[4][4];
        float ps = 0.f;
#pragma unroll
        for (int f = 0; f < 4; f++)
#pragma unroll
          for (int rr = 0; rr < 4; rr++) {
            p[f][rr] = exp2f(sf[f][rr] - mnew);
            ps += p[f][rr];
          }
        ps += __shfl_xor(ps, 16, 64);
        ps += __shfl_xor(ps, 32, 64);

        if (skip) {
          lrun += ps;
        } else {
          float sc = exp2f(mold - mnew);
          lrun = lrun * sc + ps;
#pragma unroll
          for (int rr = 0; rr < 4; rr++) {
            float scq = __shfl(sc, g * 4 + rr, 64);
#pragma unroll
            for (int f = 0; f < 4; f++) ctx[f][rr] *= scq;
          }
        }

        // P^T -> per-wave swizzled Pb (packed bf16 pairs)
#pragma unroll
        for (int f = 0; f < 4; f++)
#pragma unroll
          for (int q2 = 0; q2 < 2; q2++) {
            union { __bf16 b; u16 u; } a0, a1;
            a0.b = (__bf16)p[f][q2 * 2];
            a1.b = (__bf16)p[f][q2 * 2 + 1];
            *(uint32_t*)(PW + pwo[f][q2]) = (uint32_t)a0.u | ((uint32_t)a1.u << 16);
          }

        bf16x8 pf[2];
#pragma unroll
        for (int kh = 0; kh < 2; kh++) pf[kh] = *(const bf16x8*)(PW + pro[kh]);
        __builtin_amdgcn_s_setprio(1);
#pragma unroll
        for (int f = 0; f < 4; f++)
#pragma unroll
          for (int kh = 0; kh < 2; kh++) {
            bf16x8 vf = *(const bf16x8*)(VB + kfo[f][kh]);
            ctx[f] = __builtin_amdgcn_mfma_f32_16x16x32_bf16(pf[kh], vf, ctx[f], 0, 0, 0);
          }
        __builtin_amdgcn_s_setprio(0);
      }
      cur ^= 1;
    }

    // epilogue: lane holds ctx[q=qmin+g*4+rr][d=f*16+r16]
    float linv = 1.f / lrun;
#pragma unroll
    for (int rr = 0; rr < 4; rr++) {
      float li = __shfl(linv, g * 4 + rr, 64);
      int qg = qmin + g * 4 + rr;
#pragma unroll
      for (int f = 0; f < 4; f++) {
        union { __bf16 b; u16 u; } o;
        o.b = (__bf16)(ctx[f][rr] * li);
        ctxb[(bS + qg) * 1024 + h * 64 + f * 16 + r16] = o.u;
      }
    }
  }
#undef STAGE
}

// ---------------- in-place LayerNorm over rows of 1024 ----------------------
__global__ __launch_bounds__(256) void ln_kernel(float* __restrict__ y,
                                                 const float* __restrict__ gamma,
                                                 const float* __restrict__ beta) {
  __shared__ float sh[4];
  const int row = blockIdx.x, t = threadIdx.x;
  const int w = t >> 6, l = t & 63;
  float4 v = ((const float4*)(y + (size_t)row * 1024))[t];
  float s = v.x + v.y + v.z + v.w;
#pragma unroll
  for (int m = 32; m; m >>= 1) s += __shfl_xor(s, m, 64);
  if (l == 0) sh[w] = s;
  __syncthreads();
  float mu = (sh[0] + sh[1] + sh[2] + sh[3]) * (1.0f / 1024.0f);
  float dx = v.x - mu, dy = v.y - mu, dz = v.z - mu, dw = v.w - mu;
  float ss = dx * dx + dy * dy + dz * dz + dw * dw;
#pragma unroll
  for (int m = 32; m; m >>= 1) ss += __shfl_xor(ss, m, 64);
  __syncthreads();
  if (l == 0) sh[w] = ss;
  __syncthreads();
  float var = (sh[0] + sh[1] + sh[2] + sh[3]) * (1.0f / 1024.0f);
  float rs = rsqrtf(var + 1e-5f);
  float4 gm = ((const float4*)gamma)[t];
  float4 bt = ((const float4*)beta)[t];
  float4 o;
  o.x = dx * rs * gm.x + bt.x;
  o.y = dy * rs * gm.y + bt.y;
  o.z = dz * rs * gm.z + bt.z;
  o.w = dw * rs * gm.w + bt.w;
  ((float4*)(y + (size_t)row * 1024))[t] = o;
}

// ---------------- launcher ---------------------------------------------------
extern "C" void kernel_launch(void* const* d_in, const int* in_sizes, int n_in,
                              void* d_out, int out_size, void* d_ws, size_t ws_size,
                              hipStream_t stream) {
  (void)in_sizes; (void)n_in; (void)out_size; (void)ws_size;
  const float* x     = (const float*)d_in[0];
  const float* w1    = (const float*)d_in[1];
  const float* b1    = (const float*)d_in[2];
  const float* w2    = (const float*)d_in[3];
  const float* b2    = (const float*)d_in[4];
  const float* gamma = (const float*)d_in[5];
  const float* beta  = (const float*)d_in[6];
  float* out = (float*)d_out;

  const int M = 8192, D = 1024, N1 = 3072;

  char* ws = (char*)d_ws;
  u16* x_bf   = (u16*)(ws);                 // 16 MB; dead after gemm1
  u16* w1_bf  = (u16*)(ws + 16777216);
  u16* w2_bf  = (u16*)(ws + 23068672);
  u16* qkv_bf = (u16*)(ws + 25165824);      // 50 MB
  u16* ctx_bf = (u16*)(ws + 75497472);      // 16 MB
  u16* vtg    = (u16*)(ws);                 // reuses x_bf region (16 MB)

  cvt_kernel<<<2048, 256, 0, stream>>>(x, x_bf, M * D / 4);
  cvt_kernel<<<1024, 256, 0, stream>>>(w1, w1_bf, N1 * D / 4);
  cvt_kernel<<<512, 256, 0, stream>>>(w2, w2_bf, D * D / 4);

  gemm_bt<0><<<dim3(N1 / 128, M / 128), 256, 0, stream>>>(
      x_bf, w1_bf, b1, qkv_bf, nullptr, nullptr, M, N1, D);

  vtrans_kernel<<<dim3(32, 16, 4), 256, 0, stream>>>(qkv_bf, vtg);

  // grid: x = b*16+h (64), y = pair (8); wg%8 == bh%8 -> same-bh same-XCD
  attn_kernel<<<dim3(64, 8), 512, 0, stream>>>(qkv_bf, vtg, ctx_bf);

  gemm_bt<1><<<dim3(D / 128, M / 128), 256, 0, stream>>>(
      ctx_bf, w2_bf, b2, nullptr, out, x, M, D, D);

  ln_kernel<<<M, 256, 0, stream>>>(out, gamma, beta);
}